// Round 3
// baseline (193.158 us; speedup 1.0000x reference)
//
#include <hip/hip_runtime.h>

#define B_SZ 1024
#define DIN 512
#define HH 512   // H
#define DOUT 512
#define R_TILE 16

// ---------------------------------------------------------------------------
// prep: wb[i][j] = (j>i) ? {W_hh[i][j], b_hh[i][j]} : {0, -1}, padded to
// 512 rows (row 511 fully masked) so the scan needs no bounds checks.
// relu(0*h - 1) = 0 -> masked entries contribute nothing.
// ---------------------------------------------------------------------------
__global__ __launch_bounds__(256)
void prep_kernel(const float* __restrict__ W_hh,
                 const float* __restrict__ b_hh,
                 float2* __restrict__ wb) {
    int idx = blockIdx.x * 256 + threadIdx.x;   // over 512*512, exact grid
    int i = idx >> 9;          // 0..511
    int j = idx & 511;
    float2 o;
    if (j > i) { o.x = W_hh[idx]; o.y = b_hh[idx]; }  // i<=510 whenever j>i
    else       { o.x = 0.0f;      o.y = -1.0f;     }
    wb[idx] = o;
}

// ---------------------------------------------------------------------------
// fp32 GEMM: C = act(A[M,K] @ B[K,N] + bias). BM=64, BN=32, BK=32,
// 256 threads, 4x2 microtile, k-blocked by 4 so A-fragments are b128 reads.
// Register-relay prefetch of next K-tile + sched_barrier to pin loads.
// Grid (M/64, N/32) = 256 blocks for both GEMMs -> 1 block/CU.
// ---------------------------------------------------------------------------
template <bool ACT>
__global__ __launch_bounds__(256)
void gemm_kernel(const float* __restrict__ A,
                 const float* __restrict__ Bm,
                 const float* __restrict__ bias,
                 float* __restrict__ C,
                 int M, int N, int K) {
    __shared__ float As[64][36];   // row-major, stride 36: b128-aligned, 2-way banks
    __shared__ float Bs[32][32];

    const int tid = threadIdx.x;
    const int bm = blockIdx.x * 64;
    const int bn = blockIdx.y * 32;
    const int ty = tid >> 4;        // 0..15 -> rows 4ty..4ty+3
    const int tx = tid & 15;        // cols 2tx..2tx+1
    const int ar = tid >> 2;        // A stage row 0..63
    const int ak = (tid & 3) * 8;   // A stage k 0,8,16,24
    const int bk = tid >> 3;        // B stage k 0..31
    const int bc = (tid & 7) * 4;   // B stage col 0..28

    float4 a0, a1, b0;              // relay registers
    auto stage = [&](int kt) {
        a0 = *(const float4*)&A[(size_t)(bm + ar) * K + kt + ak];
        a1 = *(const float4*)&A[(size_t)(bm + ar) * K + kt + ak + 4];
        b0 = *(const float4*)&Bm[(size_t)(kt + bk) * N + bn + bc];
    };

    float acc[4][2] = {};

    stage(0);
    for (int kt = 0; kt < K; kt += 32) {
        __syncthreads();
        *(float4*)&As[ar][ak]     = a0;
        *(float4*)&As[ar][ak + 4] = a1;
        *(float4*)&Bs[bk][bc]     = b0;
        __syncthreads();
        if (kt + 32 < K) stage(kt + 32);
        __builtin_amdgcn_sched_barrier(0);

        #pragma unroll
        for (int k4 = 0; k4 < 32; k4 += 4) {
            float4 af[4];
            float2 bf[4];
            #pragma unroll
            for (int j = 0; j < 4; ++j) af[j] = *(const float4*)&As[4*ty + j][k4];
            #pragma unroll
            for (int u = 0; u < 4; ++u) bf[u] = *(const float2*)&Bs[k4 + u][2*tx];
            #pragma unroll
            for (int u = 0; u < 4; ++u) {
                #pragma unroll
                for (int j = 0; j < 4; ++j) {
                    const float a = (u == 0) ? af[j].x : (u == 1) ? af[j].y
                                  : (u == 2) ? af[j].z : af[j].w;
                    acc[j][0] = fmaf(a, bf[u].x, acc[j][0]);
                    acc[j][1] = fmaf(a, bf[u].y, acc[j][1]);
                }
            }
        }
    }

    #pragma unroll
    for (int j = 0; j < 4; ++j) {
        const int row = bm + 4*ty + j;
        const int col = bn + 2*tx;
        float2 v;
        v.x = acc[j][0] + bias[col + 0];
        v.y = acc[j][1] + bias[col + 1];
        if (ACT) {
            v.x = fmaxf(v.x, 0.f); v.x *= v.x;
            v.y = fmaxf(v.y, 0.f); v.y *= v.y;
        }
        *(float2*)&C[(size_t)row * N + col] = v;
    }
}

// ---------------------------------------------------------------------------
// Blocked triangular scan. 256 blocks x 4 waves; wave w owns batch row
// blockIdx*4+w; lane l owns columns l+64k (hr[8]).
// Per chunk C (64 steps):
//   diag: 64 serial steps confined to chunk-C columns; weights via an LDS
//         tile with depth-8 register prefetch (only ~25 cyc/step chain).
//   rect: dense, dependency-free accumulation of the 64 finalized h values
//         into all later columns, staged through LDS in 16-row tiles with
//         register-relay global prefetch.
// ---------------------------------------------------------------------------
template <int C>
__device__ __forceinline__ void scan_chunk(const float2* __restrict__ wb,
                                           float2* __restrict__ rect_s,
                                           float2* __restrict__ diag_s,
                                           float* __restrict__ hbuf,
                                           float hr[8], int lane, int wave,
                                           int tid) {
    // ---- stage diag tile: rows [64C,64C+64) x cols [64C,64C+64), 32 KB
    #pragma unroll
    for (int q = 0; q < 8; ++q) {
        const int e = 2 * (tid + 256 * q);      // float2 index, r*64+col
        const int r = e >> 6, col = e & 63;
        const float4 v = *(const float4*)&wb[(size_t)(64*C + r) * HH + 64*C + col];
        *(float4*)&diag_s[r * 64 + col] = v;
    }

    constexpr int Wd   = (C < 7) ? (448 - 64 * C) : 2;   // rect width (float2)
    constexpr int NLD4 = (C < 7) ? (R_TILE * Wd) / 512 : 1;
    float4 RR[NLD4];
    auto stage_rect = [&](int t) {
        #pragma unroll
        for (int q = 0; q < NLD4; ++q) {
            const int e = 2 * (tid + 256 * q);  // float2 idx in R_TILE x Wd
            const int r = e / Wd;               // constexpr divide -> magic mul
            const int col = e - r * Wd;
            RR[q] = *(const float4*)&wb[(size_t)(64*C + t*R_TILE + r) * HH
                                        + 64*(C+1) + col];
        }
    };
    if constexpr (C < 7) stage_rect(0);         // overlap with diag scan
    __syncthreads();                            // diag_s ready

    // ---- diag scan: 64 serial steps, register-prefetched weights
    float2 dreg[8];
    #pragma unroll
    for (int q = 0; q < 8; ++q) dreg[q] = diag_s[q * 64 + lane];
    for (int i8 = 0; i8 < 8; ++i8) {            // rolled: small I-footprint
        #pragma unroll
        for (int u = 0; u < 8; ++u) {
            const int i = i8 * 8 + u;
            const float2 wv = dreg[u];
            const float hi = __uint_as_float(
                __builtin_amdgcn_readlane(__float_as_uint(hr[C]), i));
            const float t  = fmaf(hi, wv.x, wv.y);
            const float rv = fmaxf(t, 0.f);
            hr[C] = fmaf(rv, rv, hr[C]);        // masked wb zeroes lanes <= i
            if (i8 < 7) dreg[u] = diag_s[(i + 8) * 64 + lane];
        }
    }

    if constexpr (C < 7) {
        hbuf[wave * 64 + lane] = hr[C];         // own-wave publish (no barrier)

        #pragma unroll 1
        for (int t = 0; t < 4; ++t) {
            __syncthreads();                    // rect_s free
            #pragma unroll
            for (int q = 0; q < NLD4; ++q) {
                const int e = 2 * (tid + 256 * q);
                const int r = e / Wd;
                const int col = e - r * Wd;
                *(float4*)&rect_s[r * 448 + col] = RR[q];
            }
            __syncthreads();                    // tile ready
            if (t + 1 < 4) stage_rect(t + 1);
            __builtin_amdgcn_sched_barrier(0);  // pin prefetch above compute

            #pragma unroll
            for (int r4 = 0; r4 < 4; ++r4) {
                const float4 h4 = *(const float4*)&hbuf[wave*64 + t*R_TILE + r4*4];
                #pragma unroll
                for (int rr = 0; rr < 4; ++rr) {
                    const float hi = (rr == 0) ? h4.x : (rr == 1) ? h4.y
                                   : (rr == 2) ? h4.z : h4.w;
                    #pragma unroll
                    for (int k = C + 1; k < 8; ++k) {
                        const float2 wv =
                            rect_s[(r4*4 + rr) * 448 + (k - C - 1) * 64 + lane];
                        const float tv = fmaf(hi, wv.x, wv.y);
                        const float rv = fmaxf(tv, 0.f);
                        hr[k] = fmaf(rv, rv, hr[k]);
                    }
                }
            }
        }
    }
}

__global__ __launch_bounds__(256, 1)
void scan_kernel(const float2* __restrict__ wb, float* __restrict__ h) {
    __shared__ float2 rect_s[R_TILE * 448];     // 56 KB
    __shared__ float2 diag_s[64 * 64];          // 32 KB
    __shared__ float  hbuf[4 * 64];             // 1 KB
    const int tid  = threadIdx.x;
    const int lane = tid & 63;
    const int wave = tid >> 6;
    const int row  = blockIdx.x * 4 + wave;     // 256 blocks x 4 waves
    float* hrow = h + (size_t)row * HH;

    float hr[8];
    #pragma unroll
    for (int k = 0; k < 8; ++k) hr[k] = hrow[lane + 64 * k];

    scan_chunk<0>(wb, rect_s, diag_s, hbuf, hr, lane, wave, tid);
    scan_chunk<1>(wb, rect_s, diag_s, hbuf, hr, lane, wave, tid);
    scan_chunk<2>(wb, rect_s, diag_s, hbuf, hr, lane, wave, tid);
    scan_chunk<3>(wb, rect_s, diag_s, hbuf, hr, lane, wave, tid);
    scan_chunk<4>(wb, rect_s, diag_s, hbuf, hr, lane, wave, tid);
    scan_chunk<5>(wb, rect_s, diag_s, hbuf, hr, lane, wave, tid);
    scan_chunk<6>(wb, rect_s, diag_s, hbuf, hr, lane, wave, tid);
    scan_chunk<7>(wb, rect_s, diag_s, hbuf, hr, lane, wave, tid);

    #pragma unroll
    for (int k = 0; k < 8; ++k) hrow[lane + 64 * k] = hr[k];
}

// ---------------------------------------------------------------------------
extern "C" void kernel_launch(void* const* d_in, const int* in_sizes, int n_in,
                              void* d_out, int out_size, void* d_ws, size_t ws_size,
                              hipStream_t stream) {
    const float* x     = (const float*)d_in[0];
    const float* W_in  = (const float*)d_in[1];
    const float* b_in  = (const float*)d_in[2];
    const float* W_hh  = (const float*)d_in[3];
    const float* b_hh  = (const float*)d_in[4];
    const float* W_out = (const float*)d_in[5];
    const float* b_out = (const float*)d_in[6];
    float* out = (float*)d_out;

    // workspace: [0,2MB) wb (512x512 float2), [2MB,4MB) h (1024x512 f32)
    float2* wb = (float2*)d_ws;
    float*  h  = (float*)((char*)d_ws + (1u << 21));

    // 1) masked padded weights: 512*512 = 1024 blocks x 256
    prep_kernel<<<dim3(1024), dim3(256), 0, stream>>>(W_hh, b_hh, wb);

    // 2) h0 = relu^2(x @ W_in + b_in)
    gemm_kernel<true><<<dim3(B_SZ / 64, HH / 32), dim3(256), 0, stream>>>(
        x, W_in, b_in, h, B_SZ, HH, DIN);

    // 3) blocked triangular scan, in-place on h
    scan_kernel<<<dim3(256), dim3(256), 0, stream>>>(wb, h);

    // 4) out = h @ W_out + b_out
    gemm_kernel<false><<<dim3(B_SZ / 64, DOUT / 32), dim3(256), 0, stream>>>(
        h, W_out, b_out, out, B_SZ, DOUT, HH);
}